// Round 13
// baseline (459.999 us; speedup 1.0000x reference)
//
#include <hip/hip_runtime.h>

// SNNEncode — numerics LOCKED (r6/r8-r12 passed, absmax 2.441406e-4):
//   xw = sequential fmaf chain k=0..15, acc init 0; LIF = exact source
//   order, separate f32 roundings, fp contract(off). DO NOT REORDER.
//
// Lessons ledger: r7/r10 wave-uniform loads scalarize -> launder via asm
// VGPR. r8/r9 LDS broadcast writeback tax. r11 pointer-lambdas kill SROA.
// r6/r9/r11/r12 all expose ~full memory latency per step-group: caused by
// (1) BRANCHES with loads in the steady loop (TOUCH/hasNext) forcing
// conservative waitcnt at merge points, (2) 1 NT store/step interleaved
// between loads (vmcnt retires IN ORDER -> load waits gated on store acks).
// r13: fully BRANCHLESS steady state + stores decoupled from the load
// window. Spikes accumulate in a rolling bit register (no runtime reg
// indexing); previous tile's 32 bits are stored 8-per-rotation. BH=2^15 so
// store addr = shift+add. Groups A-D at 6-step prefetch distance.
// block=128 (2 waves) = one b x half H; grid=256 = 1 block/CU. No LDS.

constexpr int B  = 128;
constexpr int T  = 2000;
constexpr int IN = 16;
constexpr int H  = 256;
constexpr int BH = B * H;                // 32768 = 1<<15
constexpr int TILE = 32;                 // steps per tile (1 u32 of bits)
constexpr int NTILE = 62;                // 62*32 = 1984
constexpr int TAIL = 16;                 // + 16 = 2000

typedef float f4 __attribute__((ext_vector_type(4)));

__global__ __launch_bounds__(128, 1) void snn_bl(
    const float* __restrict__ x, const float* __restrict__ Wm,
    const float* __restrict__ tau_syn, const float* __restrict__ tau_mem,
    float* __restrict__ out)
{
#pragma clang fp contract(off)
  const int tid = threadIdx.x, bid = blockIdx.x;
  const int b = bid >> 1;
  const int h = ((bid & 1) << 7) | tid;  // 0..255

  float w[IN];                           // constant indices only
#pragma unroll
  for (int k = 0; k < IN; ++k) w[k] = Wm[h * IN + k];

  float ts = tau_syn[h]; ts = ts < 0.f ? 0.f : (ts > 1.f ? 1.f : ts);
  float tm = tau_mem[h]; tm = tm < 0.f ? 0.f : (tm > 1.f ? 1.f : tm);
  const float nts = -ts;

  const char* xbc = (const char*)(x + (size_t)b * T * IN);
  const f4*   xb4 = (const f4*)xbc;      // row r = xb4[4r .. 4r+3]
  float* ob = out + (size_t)b * H + h;   // + t*BH per step (BH = 1<<15)
  float vS = 0.f, iS = 0.f;
  unsigned bits = 0u, bitsPrev = 0u;

  // 256-row bulk L2 pre-touch (prologue only; 8 f4/lane, clamped)
  auto TOUCH8 = [&](int r0) {
    const int lim = T * 4 - 1;
#pragma unroll
    for (int i = 0; i < 8; ++i) {
      int idx = r0 * 4 + tid + i * 128;
      idx = idx > lim ? lim : idx;
      f4 d = xb4[idx];
      asm volatile("" :: "v"(d.x), "v"(d.y), "v"(d.z), "v"(d.w));
    }
  };
  // 32-row steady touch (1 f4/lane, branchless, unconditional per tile)
  auto TOUCH1 = [&](int r0) {
    const int lim = T * 4 - 1;
    int idx = r0 * 4 + tid;
    idx = idx > lim ? lim : idx;
    f4 d = xb4[idx];
    asm volatile("" :: "v"(d.x), "v"(d.y), "v"(d.z), "v"(d.w));
  };

  f4 A0, A1, A2, A3, A4, A5, A6, A7;
  f4 Bg0, Bg1, Bg2, Bg3, Bg4, Bg5, Bg6, Bg7;
  f4 C0, C1, C2, C3, C4, C5, C6, C7;
  f4 D0, D1, D2, D3, D4, D5, D6, D7;

#define LOADG(P0_, P1_, P2_, P3_, P4_, P5_, P6_, P7_, r)                 \
  do {                                                                   \
    int ra_ = (r);                                                       \
    ra_ = ra_ > (T - 2) ? (T - 2) : ra_;                                 \
    int off_ = ra_ * (IN * 4);                                           \
    asm("" : "+v"(off_));                /* keep loads on vector pipe */ \
    const f4* q_ = (const f4*)(xbc + off_);                              \
    P0_ = q_[0]; P1_ = q_[1]; P2_ = q_[2]; P3_ = q_[3];                  \
    P4_ = q_[4]; P5_ = q_[5]; P6_ = q_[6]; P7_ = q_[7];                  \
  } while (0)

#define LIF1(xwv)                                                        \
  do {                                                                   \
    const float t1_ = iS - vS;                                           \
    const float t2_ = tm * t1_;                                          \
    const float vd_ = vS + t2_;                                          \
    const float xm_ = vd_ - 1.0f;                                        \
    const bool  sp_ = xm_ > 0.0f;                                        \
    vS = sp_ ? 0.0f : vd_;                                               \
    const float t3_ = nts * iS;                                          \
    const float id_ = iS + t3_;                                          \
    iS = id_ + (xwv);                                                    \
    bits = (bits >> 1) | (sp_ ? 0x80000000u : 0u);                       \
  } while (0)

#define DOT4(Q0_, Q1_, Q2_, Q3_, dst_)                                   \
  do {                                                                   \
    float a_ = 0.0f;                                                     \
    a_ = __builtin_fmaf(Q0_[0], w[0],  a_);                              \
    a_ = __builtin_fmaf(Q0_[1], w[1],  a_);                              \
    a_ = __builtin_fmaf(Q0_[2], w[2],  a_);                              \
    a_ = __builtin_fmaf(Q0_[3], w[3],  a_);                              \
    a_ = __builtin_fmaf(Q1_[0], w[4],  a_);                              \
    a_ = __builtin_fmaf(Q1_[1], w[5],  a_);                              \
    a_ = __builtin_fmaf(Q1_[2], w[6],  a_);                              \
    a_ = __builtin_fmaf(Q1_[3], w[7],  a_);                              \
    a_ = __builtin_fmaf(Q2_[0], w[8],  a_);                              \
    a_ = __builtin_fmaf(Q2_[1], w[9],  a_);                              \
    a_ = __builtin_fmaf(Q2_[2], w[10], a_);                              \
    a_ = __builtin_fmaf(Q2_[3], w[11], a_);                              \
    a_ = __builtin_fmaf(Q3_[0], w[12], a_);                              \
    a_ = __builtin_fmaf(Q3_[1], w[13], a_);                              \
    a_ = __builtin_fmaf(Q3_[2], w[14], a_);                              \
    a_ = __builtin_fmaf(Q3_[3], w[15], a_);                              \
    dst_ = a_;                                                           \
  } while (0)

#define STEP2G(P0_, P1_, P2_, P3_, P4_, P5_, P6_, P7_)                   \
  do {                                                                   \
    float xwa_, xwb_;                                                    \
    DOT4(P0_, P1_, P2_, P3_, xwa_);                                      \
    DOT4(P4_, P5_, P6_, P7_, xwb_);                                      \
    LIF1(xwa_);                                                          \
    LIF1(xwb_);                                                          \
  } while (0)

  // store 8 spikes of the PREVIOUS tile (bits 8r..8r+7), branchless clamp;
  // tile 0 harmlessly rewrites row 0 slots with 0.0 before tile 1 fixes it
#define STORE8(t0_, r_)                                                  \
  do {                                                                   \
    _Pragma("unroll")                                                    \
    for (int j_ = 0; j_ < 8; ++j_) {                                     \
      int rr_ = (t0_) - TILE + 8 * (r_) + j_;                            \
      rr_ = rr_ < 0 ? 0 : rr_;                                           \
      const float fv_ =                                                  \
          ((bitsPrev >> (8 * (r_) + j_)) & 1u) ? 1.0f : 0.0f;            \
      __builtin_nontemporal_store(fv_, ob + ((size_t)rr_ << 15));        \
    }                                                                    \
  } while (0)

  // prologue: warm 512 rows, fill groups with rows 0..7
  TOUCH8(0);
  TOUCH8(256);
  LOADG(A0, A1, A2, A3, A4, A5, A6, A7, 0);
  LOADG(Bg0, Bg1, Bg2, Bg3, Bg4, Bg5, Bg6, Bg7, 2);
  LOADG(C0, C1, C2, C3, C4, C5, C6, C7, 4);
  LOADG(D0, D1, D2, D3, D4, D5, D6, D7, 6);

#define ROT(t0_, r_)                                                     \
  do {                                                                   \
    STORE8(t0_, r_);                                                     \
    STEP2G(A0, A1, A2, A3, A4, A5, A6, A7);                              \
    LOADG(A0, A1, A2, A3, A4, A5, A6, A7, (t0_) + 8 * (r_) + 8);         \
    STEP2G(Bg0, Bg1, Bg2, Bg3, Bg4, Bg5, Bg6, Bg7);                      \
    LOADG(Bg0, Bg1, Bg2, Bg3, Bg4, Bg5, Bg6, Bg7, (t0_) + 8 * (r_) + 10);\
    STEP2G(C0, C1, C2, C3, C4, C5, C6, C7);                              \
    LOADG(C0, C1, C2, C3, C4, C5, C6, C7, (t0_) + 8 * (r_) + 12);        \
    STEP2G(D0, D1, D2, D3, D4, D5, D6, D7);                              \
    LOADG(D0, D1, D2, D3, D4, D5, D6, D7, (t0_) + 8 * (r_) + 14);        \
  } while (0)

  for (int tile = 0; tile < NTILE; ++tile) {   // branchless body
    const int t0 = tile * TILE;
    TOUCH1(t0 + 512);
    ROT(t0, 0);
    ROT(t0, 1);
    ROT(t0, 2);
    ROT(t0, 3);
    bitsPrev = bits;
  }

  // ---- tail: store tile 61's 32 bits, run 16 steps, store them ----
  {
    const int t0 = NTILE * TILE;               // 1984
#pragma unroll
    for (int j = 0; j < 32; ++j) {
      const int rr = t0 - TILE + j;            // 1952..1983
      const float fv = ((bitsPrev >> j) & 1u) ? 1.0f : 0.0f;
      __builtin_nontemporal_store(fv, ob + ((size_t)rr << 15));
    }
    STEP2G(A0, A1, A2, A3, A4, A5, A6, A7);    // rows 1984..1991
    LOADG(A0, A1, A2, A3, A4, A5, A6, A7, t0 + 8);
    STEP2G(Bg0, Bg1, Bg2, Bg3, Bg4, Bg5, Bg6, Bg7);
    LOADG(Bg0, Bg1, Bg2, Bg3, Bg4, Bg5, Bg6, Bg7, t0 + 10);
    STEP2G(C0, C1, C2, C3, C4, C5, C6, C7);
    LOADG(C0, C1, C2, C3, C4, C5, C6, C7, t0 + 12);
    STEP2G(D0, D1, D2, D3, D4, D5, D6, D7);
    LOADG(D0, D1, D2, D3, D4, D5, D6, D7, t0 + 14);
    STEP2G(A0, A1, A2, A3, A4, A5, A6, A7);    // rows 1992..1999
    STEP2G(Bg0, Bg1, Bg2, Bg3, Bg4, Bg5, Bg6, Bg7);
    STEP2G(C0, C1, C2, C3, C4, C5, C6, C7);
    STEP2G(D0, D1, D2, D3, D4, D5, D6, D7);
#pragma unroll
    for (int j = 0; j < 16; ++j) {             // steps at bits 16..31
      const int rr = t0 + j;                   // 1984..1999
      const float fv = ((bits >> (16 + j)) & 1u) ? 1.0f : 0.0f;
      __builtin_nontemporal_store(fv, ob + ((size_t)rr << 15));
    }
  }

  // final state: v_f then i_f, each [B,H] f32, after spikes
  out[(size_t)T * BH + (size_t)b * H + h]      = vS;
  out[(size_t)T * BH + BH + (size_t)b * H + h] = iS;
}

extern "C" void kernel_launch(void* const* d_in, const int* in_sizes, int n_in,
                              void* d_out, int out_size, void* d_ws, size_t ws_size,
                              hipStream_t stream) {
  const float* x  = (const float*)d_in[0];
  const float* W  = (const float*)d_in[1];
  const float* ts = (const float*)d_in[2];
  const float* tm = (const float*)d_in[3];
  float* out = (float*)d_out;
  hipLaunchKernelGGL(snn_bl, dim3(B * 2), dim3(128), 0, stream,
                     x, W, ts, tm, out);
}